// Round 1
// baseline (5626.206 us; speedup 1.0000x reference)
//
#include <hip/hip_runtime.h>
#include <hip/hip_bf16.h>

// GCN, 3x GraphConv(norm='both') + 4->2 linear + softmax.
// N=1e6 nodes, E=8e6 edges, feature widths 1->4->4->4->2.
// Strategy: node-parallel "project" kernels (epilogue of previous layer fused),
// edge-parallel scatter with float atomics, everything f32.

__global__ void count_deg_kernel(const int* __restrict__ src, const int* __restrict__ dst,
                                 float* __restrict__ dsrc, float* __restrict__ ddst, int E) {
    int i = blockIdx.x * blockDim.x + threadIdx.x;
    if (i < E) {
        atomicAdd(&dsrc[src[i]], 1.0f);
        atomicAdd(&ddst[dst[i]], 1.0f);
    }
}

__global__ void finalize_norm_kernel(float* __restrict__ ns, float* __restrict__ nd, int N) {
    int i = blockIdx.x * blockDim.x + threadIdx.x;
    if (i < N) {
        float d = ns[i]; ns[i] = d > 0.f ? rsqrtf(d) : 0.f;
        float e = nd[i]; nd[i] = e > 0.f ? rsqrtf(e) : 0.f;
    }
}

// Layer 1: x [N,1] -> h [N,4]:  h[i][c] = x[i]*ns[i]*W1[c]
__global__ void h1_kernel(const float* __restrict__ x, const float* __restrict__ ns,
                          const float* __restrict__ W, float4* __restrict__ h, int N) {
    int i = blockIdx.x * blockDim.x + threadIdx.x;
    if (i < N) {
        float v = x[i] * ns[i];
        float4 o;
        o.x = v * W[0]; o.y = v * W[1]; o.z = v * W[2]; o.w = v * W[3];
        h[i] = o;
    }
}

// Layers 2/3: fuse previous layer's epilogue (agg*nd + b, ReLU) with this
// layer's ns scale and 4x4 projection. W row-major [4][4].
__global__ void h_kernel(const float4* __restrict__ agg, const float* __restrict__ ns,
                         const float* __restrict__ nd, const float* __restrict__ bias,
                         const float* __restrict__ W, float4* __restrict__ h, int N) {
    int i = blockIdx.x * blockDim.x + threadIdx.x;
    if (i < N) {
        float4 a = agg[i];
        float s = nd[i];
        float x0 = fmaxf(a.x * s + bias[0], 0.f);
        float x1 = fmaxf(a.y * s + bias[1], 0.f);
        float x2 = fmaxf(a.z * s + bias[2], 0.f);
        float x3 = fmaxf(a.w * s + bias[3], 0.f);
        float t = ns[i];
        x0 *= t; x1 *= t; x2 *= t; x3 *= t;
        float4 o;
        o.x = x0*W[0] + x1*W[4] + x2*W[8]  + x3*W[12];
        o.y = x0*W[1] + x1*W[5] + x2*W[9]  + x3*W[13];
        o.z = x0*W[2] + x1*W[6] + x2*W[10] + x3*W[14];
        o.w = x0*W[3] + x1*W[7] + x2*W[11] + x3*W[15];
        h[i] = o;
    }
}

// Edge scatter: agg[dst[e]] += h[src[e]] (4 channels)
__global__ void scatter_kernel(const float4* __restrict__ h, const int* __restrict__ src,
                               const int* __restrict__ dst, float* __restrict__ agg, int E) {
    int e = blockIdx.x * blockDim.x + threadIdx.x;
    if (e < E) {
        float4 v = h[src[e]];
        float* p = agg + 4ll * dst[e];
        atomicAdd(p + 0, v.x);
        atomicAdd(p + 1, v.y);
        atomicAdd(p + 2, v.z);
        atomicAdd(p + 3, v.w);
    }
}

// Final: layer-3 epilogue (no ReLU) + [4,2] linear + softmax over 2 classes.
__global__ void final_kernel(const float4* __restrict__ agg, const float* __restrict__ nd,
                             const float* __restrict__ bias, const float* __restrict__ Wl,
                             const float* __restrict__ bl, float2* __restrict__ out, int N) {
    int i = blockIdx.x * blockDim.x + threadIdx.x;
    if (i < N) {
        float4 a = agg[i];
        float s = nd[i];
        float x0 = a.x * s + bias[0];
        float x1 = a.y * s + bias[1];
        float x2 = a.z * s + bias[2];
        float x3 = a.w * s + bias[3];
        float z0 = x0*Wl[0] + x1*Wl[2] + x2*Wl[4] + x3*Wl[6] + bl[0];
        float z1 = x0*Wl[1] + x1*Wl[3] + x2*Wl[5] + x3*Wl[7] + bl[1];
        float m  = fmaxf(z0, z1);
        float e0 = expf(z0 - m), e1 = expf(z1 - m);
        float inv = 1.f / (e0 + e1);
        out[i] = make_float2(e0 * inv, e1 * inv);
    }
}

extern "C" void kernel_launch(void* const* d_in, const int* in_sizes, int n_in,
                              void* d_out, int out_size, void* d_ws, size_t ws_size,
                              hipStream_t stream) {
    const float* in_feat = (const float*)d_in[0];
    const int*   src     = (const int*)d_in[1];
    const int*   dst     = (const int*)d_in[2];
    const float* W1 = (const float*)d_in[3];
    const float* b1 = (const float*)d_in[4];
    const float* W2 = (const float*)d_in[5];
    const float* b2 = (const float*)d_in[6];
    const float* W3 = (const float*)d_in[7];
    const float* b3 = (const float*)d_in[8];
    const float* Wl = (const float*)d_in[9];
    const float* bl = (const float*)d_in[10];

    const int N = in_sizes[0];   // 1,000,000
    const int E = in_sizes[1];   // 8,000,000

    // Workspace layout (floats): ns[N] | nd[N] | A[N*4] | B[N*4]  (40 MB)
    float*  ws = (float*)d_ws;
    float*  ns = ws;
    float*  nd = ws + (size_t)N;
    float4* A  = (float4*)(ws + 2ull * N);
    float4* B  = (float4*)(ws + 2ull * N + 4ull * N);

    const int BT = 256;
    const int gridN = (N + BT - 1) / BT;
    const int gridE = (E + BT - 1) / BT;

    // Degree norms
    hipMemsetAsync(ns, 0, 2ull * N * sizeof(float), stream);
    count_deg_kernel<<<gridE, BT, 0, stream>>>(src, dst, ns, nd, E);
    finalize_norm_kernel<<<gridN, BT, 0, stream>>>(ns, nd, N);

    // Layer 1: in_feat -> A(h) -> B(agg)
    h1_kernel<<<gridN, BT, 0, stream>>>(in_feat, ns, W1, A, N);
    hipMemsetAsync(B, 0, 4ull * N * sizeof(float), stream);
    scatter_kernel<<<gridE, BT, 0, stream>>>(A, src, dst, (float*)B, E);

    // Layer 2: B(agg) -> A(h) -> B(agg)
    h_kernel<<<gridN, BT, 0, stream>>>(B, ns, nd, b1, W2, A, N);
    hipMemsetAsync(B, 0, 4ull * N * sizeof(float), stream);
    scatter_kernel<<<gridE, BT, 0, stream>>>(A, src, dst, (float*)B, E);

    // Layer 3: B(agg) -> A(h) -> B(agg)
    h_kernel<<<gridN, BT, 0, stream>>>(B, ns, nd, b2, W3, A, N);
    hipMemsetAsync(B, 0, 4ull * N * sizeof(float), stream);
    scatter_kernel<<<gridE, BT, 0, stream>>>(A, src, dst, (float*)B, E);

    // Final linear + softmax
    final_kernel<<<gridN, BT, 0, stream>>>(B, nd, b3, Wl, bl, (float2*)d_out, N);
}

// Round 2
// 1993.144 us; speedup vs baseline: 2.8228x; 2.8228x over previous
//
#include <hip/hip_runtime.h>
#include <hip/hip_bf16.h>

// GCN: 3x GraphConv(norm='both') + 4->2 linear + softmax.
// Round 2: replace push-scatter (32M f32 atomics/layer) with per-call dst-CSR
// build + atomic-free pull-gather per layer. Epilogue of layer k and the
// projection of layer k+1 are fused into each gather kernel.

#define BT 256

// ---------------- CSR path ----------------

__global__ void count_kernel(const int* __restrict__ src, const int* __restrict__ dst,
                             int* __restrict__ degs, int* __restrict__ degd, int E) {
    int i = blockIdx.x * blockDim.x + threadIdx.x;
    if (i < E) {
        atomicAdd(&degs[src[i]], 1);
        atomicAdd(&degd[dst[i]], 1);
    }
}

// ns/nd from degrees, sx = x*ns, and CSR segment allocation via wave
// prefix-scan + one atomic per wave (avoids 1M serialized single-address atomics).
__global__ void finalize_alloc_kernel(const int* __restrict__ degs, const int* __restrict__ degd,
                                      const float* __restrict__ x,
                                      float* __restrict__ ns, float* __restrict__ nd,
                                      float* __restrict__ sx, int* __restrict__ start,
                                      int* __restrict__ cursor, int N) {
    int i = blockIdx.x * blockDim.x + threadIdx.x;
    int lane = threadIdx.x & 63;
    int dd = 0;
    if (i < N) {
        int ds = degs[i];
        float nsv = ds > 0 ? rsqrtf((float)ds) : 0.f;
        ns[i] = nsv;
        dd = degd[i];
        nd[i] = dd > 0 ? rsqrtf((float)dd) : 0.f;
        sx[i] = x[i] * nsv;
    }
    // inclusive wave prefix of dd
    int pre = dd;
    #pragma unroll
    for (int off = 1; off < 64; off <<= 1) {
        int t = __shfl_up(pre, off);
        if (lane >= off) pre += t;
    }
    int total = __shfl(pre, 63);
    int base = 0;
    if (lane == 63 && total > 0) base = atomicAdd(cursor, total);
    base = __shfl(base, 63);
    if (i < N) start[i] = base + pre - dd;   // exclusive prefix within segment pool
}

// eidx[pos] = src, bucketed by dst. After this, start[i] == segment end.
__global__ void fill_kernel(const int* __restrict__ src, const int* __restrict__ dst,
                            int* __restrict__ start, int* __restrict__ eidx, int E) {
    int i = blockIdx.x * blockDim.x + threadIdx.x;
    if (i < E) {
        int p = atomicAdd(&start[dst[i]], 1);
        eidx[p] = src[i];
    }
}

// Layer 1 (rank-1: h1 = sx * W1) gather + epilogue + W2 projection -> A (= h2)
__global__ void gather1_kernel(const float* __restrict__ sx, const int* __restrict__ eidx,
                               const int* __restrict__ endp, const int* __restrict__ deg,
                               const float* __restrict__ ns, const float* __restrict__ nd,
                               const float* __restrict__ W1, const float* __restrict__ b1,
                               const float* __restrict__ W2,
                               float4* __restrict__ A, int N) {
    int i = blockIdx.x * blockDim.x + threadIdx.x;
    if (i >= N) return;
    int e = endp[i], d = deg[i];
    float sum = 0.f;
    for (int k = e - d; k < e; ++k) sum += sx[eidx[k]];
    float t = sum * nd[i];
    float nsv = ns[i];
    float x0 = fmaxf(t * W1[0] + b1[0], 0.f) * nsv;
    float x1 = fmaxf(t * W1[1] + b1[1], 0.f) * nsv;
    float x2 = fmaxf(t * W1[2] + b1[2], 0.f) * nsv;
    float x3 = fmaxf(t * W1[3] + b1[3], 0.f) * nsv;
    float4 o;
    o.x = x0*W2[0] + x1*W2[4] + x2*W2[8]  + x3*W2[12];
    o.y = x0*W2[1] + x1*W2[5] + x2*W2[9]  + x3*W2[13];
    o.z = x0*W2[2] + x1*W2[6] + x2*W2[10] + x3*W2[14];
    o.w = x0*W2[3] + x1*W2[7] + x2*W2[11] + x3*W2[15];
    A[i] = o;
}

// Layer 2 gather (float4) + epilogue(b, relu) + W projection -> B (= h3)
__global__ void gather4_kernel(const float4* __restrict__ H, const int* __restrict__ eidx,
                               const int* __restrict__ endp, const int* __restrict__ deg,
                               const float* __restrict__ ns, const float* __restrict__ nd,
                               const float* __restrict__ b, const float* __restrict__ W,
                               float4* __restrict__ out, int N) {
    int i = blockIdx.x * blockDim.x + threadIdx.x;
    if (i >= N) return;
    int e = endp[i], d = deg[i];
    float s0 = 0.f, s1 = 0.f, s2 = 0.f, s3 = 0.f;
    for (int k = e - d; k < e; ++k) {
        float4 v = H[eidx[k]];
        s0 += v.x; s1 += v.y; s2 += v.z; s3 += v.w;
    }
    float nv = nd[i], nsv = ns[i];
    float x0 = fmaxf(s0 * nv + b[0], 0.f) * nsv;
    float x1 = fmaxf(s1 * nv + b[1], 0.f) * nsv;
    float x2 = fmaxf(s2 * nv + b[2], 0.f) * nsv;
    float x3 = fmaxf(s3 * nv + b[3], 0.f) * nsv;
    float4 o;
    o.x = x0*W[0] + x1*W[4] + x2*W[8]  + x3*W[12];
    o.y = x0*W[1] + x1*W[5] + x2*W[9]  + x3*W[13];
    o.z = x0*W[2] + x1*W[6] + x2*W[10] + x3*W[14];
    o.w = x0*W[3] + x1*W[7] + x2*W[11] + x3*W[15];
    out[i] = o;
}

// Layer 3 gather + epilogue (no relu) + [4,2] linear + softmax -> out
__global__ void gatherF_kernel(const float4* __restrict__ H, const int* __restrict__ eidx,
                               const int* __restrict__ endp, const int* __restrict__ deg,
                               const float* __restrict__ nd, const float* __restrict__ b,
                               const float* __restrict__ Wl, const float* __restrict__ bl,
                               float2* __restrict__ out, int N) {
    int i = blockIdx.x * blockDim.x + threadIdx.x;
    if (i >= N) return;
    int e = endp[i], d = deg[i];
    float s0 = 0.f, s1 = 0.f, s2 = 0.f, s3 = 0.f;
    for (int k = e - d; k < e; ++k) {
        float4 v = H[eidx[k]];
        s0 += v.x; s1 += v.y; s2 += v.z; s3 += v.w;
    }
    float nv = nd[i];
    float x0 = s0 * nv + b[0];
    float x1 = s1 * nv + b[1];
    float x2 = s2 * nv + b[2];
    float x3 = s3 * nv + b[3];
    float z0 = x0*Wl[0] + x1*Wl[2] + x2*Wl[4] + x3*Wl[6] + bl[0];
    float z1 = x0*Wl[1] + x1*Wl[3] + x2*Wl[5] + x3*Wl[7] + bl[1];
    float m  = fmaxf(z0, z1);
    float e0 = expf(z0 - m), e1 = expf(z1 - m);
    float inv = 1.f / (e0 + e1);
    out[i] = make_float2(e0 * inv, e1 * inv);
}

// ---------------- fallback (round-1 push-scatter) ----------------

__global__ void fb_count_deg(const int* __restrict__ src, const int* __restrict__ dst,
                             float* __restrict__ dsrc, float* __restrict__ ddst, int E) {
    int i = blockIdx.x * blockDim.x + threadIdx.x;
    if (i < E) { atomicAdd(&dsrc[src[i]], 1.0f); atomicAdd(&ddst[dst[i]], 1.0f); }
}
__global__ void fb_finalize(float* __restrict__ ns, float* __restrict__ nd, int N) {
    int i = blockIdx.x * blockDim.x + threadIdx.x;
    if (i < N) {
        float d = ns[i]; ns[i] = d > 0.f ? rsqrtf(d) : 0.f;
        float e = nd[i]; nd[i] = e > 0.f ? rsqrtf(e) : 0.f;
    }
}
__global__ void fb_h1(const float* __restrict__ x, const float* __restrict__ ns,
                      const float* __restrict__ W, float4* __restrict__ h, int N) {
    int i = blockIdx.x * blockDim.x + threadIdx.x;
    if (i < N) {
        float v = x[i] * ns[i];
        h[i] = make_float4(v*W[0], v*W[1], v*W[2], v*W[3]);
    }
}
__global__ void fb_h(const float4* __restrict__ agg, const float* __restrict__ ns,
                     const float* __restrict__ nd, const float* __restrict__ bias,
                     const float* __restrict__ W, float4* __restrict__ h, int N) {
    int i = blockIdx.x * blockDim.x + threadIdx.x;
    if (i < N) {
        float4 a = agg[i]; float s = nd[i], t = ns[i];
        float x0 = fmaxf(a.x*s + bias[0], 0.f)*t;
        float x1 = fmaxf(a.y*s + bias[1], 0.f)*t;
        float x2 = fmaxf(a.z*s + bias[2], 0.f)*t;
        float x3 = fmaxf(a.w*s + bias[3], 0.f)*t;
        float4 o;
        o.x = x0*W[0]+x1*W[4]+x2*W[8]+x3*W[12];
        o.y = x0*W[1]+x1*W[5]+x2*W[9]+x3*W[13];
        o.z = x0*W[2]+x1*W[6]+x2*W[10]+x3*W[14];
        o.w = x0*W[3]+x1*W[7]+x2*W[11]+x3*W[15];
        h[i] = o;
    }
}
__global__ void fb_scatter(const float4* __restrict__ h, const int* __restrict__ src,
                           const int* __restrict__ dst, float* __restrict__ agg, int E) {
    int e = blockIdx.x * blockDim.x + threadIdx.x;
    if (e < E) {
        float4 v = h[src[e]];
        float* p = agg + 4ll * dst[e];
        atomicAdd(p+0, v.x); atomicAdd(p+1, v.y);
        atomicAdd(p+2, v.z); atomicAdd(p+3, v.w);
    }
}
__global__ void fb_final(const float4* __restrict__ agg, const float* __restrict__ nd,
                         const float* __restrict__ bias, const float* __restrict__ Wl,
                         const float* __restrict__ bl, float2* __restrict__ out, int N) {
    int i = blockIdx.x * blockDim.x + threadIdx.x;
    if (i < N) {
        float4 a = agg[i]; float s = nd[i];
        float x0 = a.x*s + bias[0], x1 = a.y*s + bias[1];
        float x2 = a.z*s + bias[2], x3 = a.w*s + bias[3];
        float z0 = x0*Wl[0]+x1*Wl[2]+x2*Wl[4]+x3*Wl[6]+bl[0];
        float z1 = x0*Wl[1]+x1*Wl[3]+x2*Wl[5]+x3*Wl[7]+bl[1];
        float m = fmaxf(z0, z1);
        float e0 = expf(z0-m), e1 = expf(z1-m);
        float inv = 1.f/(e0+e1);
        out[i] = make_float2(e0*inv, e1*inv);
    }
}

extern "C" void kernel_launch(void* const* d_in, const int* in_sizes, int n_in,
                              void* d_out, int out_size, void* d_ws, size_t ws_size,
                              hipStream_t stream) {
    const float* in_feat = (const float*)d_in[0];
    const int*   src     = (const int*)d_in[1];
    const int*   dst     = (const int*)d_in[2];
    const float* W1 = (const float*)d_in[3];
    const float* b1 = (const float*)d_in[4];
    const float* W2 = (const float*)d_in[5];
    const float* b2 = (const float*)d_in[6];
    const float* W3 = (const float*)d_in[7];
    const float* b3 = (const float*)d_in[8];
    const float* Wl = (const float*)d_in[9];
    const float* bl = (const float*)d_in[10];

    const int N = in_sizes[0];
    const int E = in_sizes[1];

    const int gridN = (N + BT - 1) / BT;
    const int gridE = (E + BT - 1) / BT;

    // CSR-path workspace: ns|nd|sx (f32 N each) | deg|start (i32 N each)
    //                   | A (f32 4N) | B (f32 4N) | eidx (i32 E) | cursor
    size_t need = ((size_t)13 * N + E + 16) * 4;

    if (ws_size >= need) {
        float* ws   = (float*)d_ws;
        float* ns   = ws;
        float* nd   = ws + (size_t)N;
        float* sx   = ws + 2ull * N;
        int*   deg  = (int*)(ws + 3ull * N);
        int*   start= (int*)(ws + 4ull * N);
        float4* A   = (float4*)(ws + 5ull * N);
        float4* B   = (float4*)(ws + 9ull * N);
        int*   eidx = (int*)(ws + 13ull * N);
        int*   cursor = eidx + (size_t)E;
        int*   degs = (int*)A;   // temp src-degree aliases A (consumed before A written)

        hipMemsetAsync(deg, 0, (size_t)N * sizeof(int), stream);
        hipMemsetAsync(degs, 0, (size_t)N * sizeof(int), stream);
        hipMemsetAsync(cursor, 0, sizeof(int), stream);

        count_kernel<<<gridE, BT, 0, stream>>>(src, dst, degs, deg, E);
        finalize_alloc_kernel<<<gridN, BT, 0, stream>>>(degs, deg, in_feat,
                                                        ns, nd, sx, start, cursor, N);
        fill_kernel<<<gridE, BT, 0, stream>>>(src, dst, start, eidx, E);
        // start[i] now holds segment END; deg[i] gives length.
        gather1_kernel<<<gridN, BT, 0, stream>>>(sx, eidx, start, deg, ns, nd,
                                                 W1, b1, W2, A, N);
        gather4_kernel<<<gridN, BT, 0, stream>>>(A, eidx, start, deg, ns, nd,
                                                 b2, W3, B, N);
        gatherF_kernel<<<gridN, BT, 0, stream>>>(B, eidx, start, deg, nd,
                                                 b3, Wl, bl, (float2*)d_out, N);
    } else {
        // round-1 fallback (40 MB)
        float*  ws = (float*)d_ws;
        float*  ns = ws;
        float*  nd = ws + (size_t)N;
        float4* A  = (float4*)(ws + 2ull * N);
        float4* B  = (float4*)(ws + 2ull * N + 4ull * N);

        hipMemsetAsync(ns, 0, 2ull * N * sizeof(float), stream);
        fb_count_deg<<<gridE, BT, 0, stream>>>(src, dst, ns, nd, E);
        fb_finalize<<<gridN, BT, 0, stream>>>(ns, nd, N);
        fb_h1<<<gridN, BT, 0, stream>>>(in_feat, ns, W1, A, N);
        hipMemsetAsync(B, 0, 4ull * N * sizeof(float), stream);
        fb_scatter<<<gridE, BT, 0, stream>>>(A, src, dst, (float*)B, E);
        fb_h<<<gridN, BT, 0, stream>>>(B, ns, nd, b1, W2, A, N);
        hipMemsetAsync(B, 0, 4ull * N * sizeof(float), stream);
        fb_scatter<<<gridE, BT, 0, stream>>>(A, src, dst, (float*)B, E);
        fb_h<<<gridN, BT, 0, stream>>>(B, ns, nd, b2, W3, A, N);
        hipMemsetAsync(B, 0, 4ull * N * sizeof(float), stream);
        fb_scatter<<<gridE, BT, 0, stream>>>(A, src, dst, (float*)B, E);
        fb_final<<<gridN, BT, 0, stream>>>(B, nd, b3, Wl, bl, (float2*)d_out, N);
    }
}